// Round 11
// baseline (237.522 us; speedup 1.0000x reference)
//
#include <hip/hip_runtime.h>
#include <stdint.h>

#define NN 4096
#define NGG 4096
#define NUU 8192

// monotone float->uint mapping (order-preserving incl. negatives)
__device__ __forceinline__ unsigned fkey32(float f) {
  unsigned u = __float_as_uint(f);
  return u ^ (((int)u >> 31) | 0x80000000u);
}
__device__ __forceinline__ float unfkey32(unsigned k) {
  unsigned m = (k & 0x80000000u) ? 0x80000000u : 0xFFFFFFFFu;
  return __uint_as_float(k ^ m);
}

// ---------------- block-wide sum (blockDim.x == 256) -------------------
__device__ __forceinline__ float block_sum_256(float v, float* sbuf) {
#pragma unroll
  for (int o = 32; o > 0; o >>= 1) v += __shfl_down(v, o, 64);
  int lane = threadIdx.x & 63;
  int w = threadIdx.x >> 6;
  if (lane == 0) sbuf[w] = v;
  __syncthreads();
  float r = 0.f;
  if (threadIdx.x == 0) r = sbuf[0] + sbuf[1] + sbuf[2] + sbuf[3];
  __syncthreads();
  return r;
}

// ---------------- block-wide sum (blockDim.x == 512) -------------------
__device__ __forceinline__ float block_sum_512(float v, float* sbuf) {
#pragma unroll
  for (int o = 32; o > 0; o >>= 1) v += __shfl_down(v, o, 64);
  int lane = threadIdx.x & 63;
  int w = threadIdx.x >> 6;
  if (lane == 0) sbuf[w] = v;
  __syncthreads();
  float r = 0.f;
  if (threadIdx.x == 0) {
#pragma unroll
    for (int i = 0; i < 8; ++i) r += sbuf[i];
  }
  __syncthreads();
  return r;
}

// ---------------- fused scan: argmin + chamfer rows + chamfer cols -----
// R2-proven layout (Q=4, 1280 blocks, 256 thr). Block 0 zeroes acc.
__global__ __launch_bounds__(256) void k_scan(const float* __restrict__ pts,
                                              const float* __restrict__ gt,
                                              const float* __restrict__ up,
                                              const float* __restrict__ off,
                                              unsigned long long* __restrict__ keys,
                                              unsigned* __restrict__ rowmin,
                                              unsigned* __restrict__ colmin,
                                              float* __restrict__ acc) {
  __shared__ float4 sc[512];   // 8 KB
  int blk = blockIdx.x;
  int tid = threadIdx.x;
  if (blk == 0 && tid < 16) acc[tid] = 0.f;

  if (blk < 512) {
    // ------- cham_row: up/off points vs gt candidates -------
    int qb = blk >> 3;           // [0,64)
    int seg = blk & 7;           // [0,8)
    int wb = qb >> 3;            // [0,8)
    int which = wb >> 2;         // 0=off, 1=up
    int b = wb & 3;
    int r0 = (qb & 7) * 1024 + tid * 4;   // [0,8192)
    {
      const float* gtb = gt + (size_t)b * NGG * 6 + (size_t)seg * 512 * 6;
      int i0 = tid * 2;
      const float4* g4 = (const float4*)(gtb + (size_t)i0 * 6);
      float4 u0 = g4[0], u1 = g4[1], u2 = g4[2];
      sc[i0] = make_float4(u0.x, u0.y, u0.z,
                           fmaf(u0.x, u0.x, fmaf(u0.y, u0.y, u0.z * u0.z)));
      sc[i0 + 1] = make_float4(u1.z, u1.w, u2.x,
                               fmaf(u1.z, u1.z, fmaf(u1.w, u1.w, u2.x * u2.x)));
    }
    const float* src = which ? up : off;
    const float4* s4 = (const float4*)src;
    size_t fb = ((size_t)(b * NUU + r0) * 3) >> 2;
    float4 A = s4[fb], B = s4[fb + 1], C = s4[fb + 2];
    float q0x = A.x, q0y = A.y, q0z = A.z;
    float q1x = A.w, q1y = B.x, q1z = B.y;
    float q2x = B.z, q2y = B.w, q2z = C.x;
    float q3x = C.y, q3y = C.z, q3z = C.w;
    float qq0 = fmaf(q0x, q0x, fmaf(q0y, q0y, q0z * q0z));
    float qq1 = fmaf(q1x, q1x, fmaf(q1y, q1y, q1z * q1z));
    float qq2 = fmaf(q2x, q2x, fmaf(q2y, q2y, q2z * q2z));
    float qq3 = fmaf(q3x, q3x, fmaf(q3y, q3y, q3z * q3z));
    float a0x = -2.f * q0x, a0y = -2.f * q0y, a0z = -2.f * q0z;
    float a1x = -2.f * q1x, a1y = -2.f * q1y, a1z = -2.f * q1z;
    float a2x = -2.f * q2x, a2y = -2.f * q2y, a2z = -2.f * q2z;
    float a3x = -2.f * q3x, a3y = -2.f * q3y, a3z = -2.f * q3z;
    __syncthreads();
    float b0 = 3.4e38f, b1 = 3.4e38f, b2 = 3.4e38f, b3 = 3.4e38f;
#pragma unroll 4
    for (int j = 0; j < 512; ++j) {
      float4 c = sc[j];
      float t;
      t = fmaf(c.x, a0x, c.w); t = fmaf(c.y, a0y, t); t = fmaf(c.z, a0z, t); b0 = fminf(b0, t);
      t = fmaf(c.x, a1x, c.w); t = fmaf(c.y, a1y, t); t = fmaf(c.z, a1z, t); b1 = fminf(b1, t);
      t = fmaf(c.x, a2x, c.w); t = fmaf(c.y, a2y, t); t = fmaf(c.z, a2z, t); b2 = fminf(b2, t);
      t = fmaf(c.x, a3x, c.w); t = fmaf(c.y, a3y, t); t = fmaf(c.z, a3z, t); b3 = fminf(b3, t);
    }
    int gr = which * 32768 + b * NUU + r0;
    atomicMin(&rowmin[gr + 0], fkey32(b0 + qq0));
    atomicMin(&rowmin[gr + 1], fkey32(b1 + qq1));
    atomicMin(&rowmin[gr + 2], fkey32(b2 + qq2));
    atomicMin(&rowmin[gr + 3], fkey32(b3 + qq3));

  } else if (blk < 1024) {
    // ------- cham_col: gt points vs up/off candidates -------
    int blk2 = blk - 512;
    int qb = blk2 >> 4;          // [0,32)
    int seg = blk2 & 15;         // [0,16)
    int which = qb >> 4;         // 0=off, 1=up
    int b = (qb >> 2) & 3;
    int m0 = (qb & 3) * 1024 + tid * 4;   // [0,4096)
    const float* src = which ? up : off;
    if (tid < 128) {
      const float* sb = src + (size_t)b * NUU * 3 + (size_t)seg * 512 * 3;
      int i0 = tid * 4;
      const float4* s4 = (const float4*)(sb + (size_t)i0 * 3);
      float4 u0 = s4[0], u1 = s4[1], u2 = s4[2];
      sc[i0] = make_float4(u0.x, u0.y, u0.z,
                           fmaf(u0.x, u0.x, fmaf(u0.y, u0.y, u0.z * u0.z)));
      sc[i0 + 1] = make_float4(u0.w, u1.x, u1.y,
                               fmaf(u0.w, u0.w, fmaf(u1.x, u1.x, u1.y * u1.y)));
      sc[i0 + 2] = make_float4(u1.z, u1.w, u2.x,
                               fmaf(u1.z, u1.z, fmaf(u1.w, u1.w, u2.x * u2.x)));
      sc[i0 + 3] = make_float4(u2.y, u2.z, u2.w,
                               fmaf(u2.y, u2.y, fmaf(u2.z, u2.z, u2.w * u2.w)));
    }
    const float* g = gt + (size_t)b * NGG * 6 + (size_t)m0 * 6;
    float q0x = g[0],  q0y = g[1],  q0z = g[2];
    float q1x = g[6],  q1y = g[7],  q1z = g[8];
    float q2x = g[12], q2y = g[13], q2z = g[14];
    float q3x = g[18], q3y = g[19], q3z = g[20];
    float qq0 = fmaf(q0x, q0x, fmaf(q0y, q0y, q0z * q0z));
    float qq1 = fmaf(q1x, q1x, fmaf(q1y, q1y, q1z * q1z));
    float qq2 = fmaf(q2x, q2x, fmaf(q2y, q2y, q2z * q2z));
    float qq3 = fmaf(q3x, q3x, fmaf(q3y, q3y, q3z * q3z));
    float a0x = -2.f * q0x, a0y = -2.f * q0y, a0z = -2.f * q0z;
    float a1x = -2.f * q1x, a1y = -2.f * q1y, a1z = -2.f * q1z;
    float a2x = -2.f * q2x, a2y = -2.f * q2y, a2z = -2.f * q2z;
    float a3x = -2.f * q3x, a3y = -2.f * q3y, a3z = -2.f * q3z;
    __syncthreads();
    float b0 = 3.4e38f, b1 = 3.4e38f, b2 = 3.4e38f, b3 = 3.4e38f;
#pragma unroll 4
    for (int j = 0; j < 512; ++j) {
      float4 c = sc[j];
      float t;
      t = fmaf(c.x, a0x, c.w); t = fmaf(c.y, a0y, t); t = fmaf(c.z, a0z, t); b0 = fminf(b0, t);
      t = fmaf(c.x, a1x, c.w); t = fmaf(c.y, a1y, t); t = fmaf(c.z, a1z, t); b1 = fminf(b1, t);
      t = fmaf(c.x, a2x, c.w); t = fmaf(c.y, a2y, t); t = fmaf(c.z, a2z, t); b2 = fminf(b2, t);
      t = fmaf(c.x, a3x, c.w); t = fmaf(c.y, a3y, t); t = fmaf(c.z, a3z, t); b3 = fminf(b3, t);
    }
    int gc = which * 16384 + b * NGG + m0;
    atomicMin(&colmin[gc + 0], fkey32(b0 + qq0));
    atomicMin(&colmin[gc + 1], fkey32(b1 + qq1));
    atomicMin(&colmin[gc + 2], fkey32(b2 + qq2));
    atomicMin(&colmin[gc + 3], fkey32(b3 + qq3));

  } else {
    // ------- argmin: pts vs gt candidates (keyed: dist<<32 | idx) -------
    int blk3 = blk - 1024;
    int qb = blk3 >> 4;          // [0,16)
    int seg = blk3 & 15;         // [0,16), 256 candidates each
    int b = qb >> 2;
    int m0 = (qb & 3) * 1024 + tid * 4;   // [0,4096)
    if (tid < 128) {
      const float* gtb = gt + (size_t)b * NGG * 6 + (size_t)seg * 256 * 6;
      int i0 = tid * 2;
      const float4* g4 = (const float4*)(gtb + (size_t)i0 * 6);
      float4 u0 = g4[0], u1 = g4[1], u2 = g4[2];
      sc[i0] = make_float4(u0.x, u0.y, u0.z,
                           fmaf(u0.x, u0.x, fmaf(u0.y, u0.y, u0.z * u0.z)));
      sc[i0 + 1] = make_float4(u1.z, u1.w, u2.x,
                               fmaf(u1.z, u1.z, fmaf(u1.w, u1.w, u2.x * u2.x)));
    }
    size_t fb = ((size_t)(b * NN + m0) * 3) >> 2;
    const float4* p4 = (const float4*)pts;
    float4 A = p4[fb], B = p4[fb + 1], C = p4[fb + 2];
    float q0x = A.x, q0y = A.y, q0z = A.z;
    float q1x = A.w, q1y = B.x, q1z = B.y;
    float q2x = B.z, q2y = B.w, q2z = C.x;
    float q3x = C.y, q3y = C.z, q3z = C.w;
    float a0x = -2.f * q0x, a0y = -2.f * q0y, a0z = -2.f * q0z;
    float a1x = -2.f * q1x, a1y = -2.f * q1y, a1z = -2.f * q1z;
    float a2x = -2.f * q2x, a2y = -2.f * q2y, a2z = -2.f * q2z;
    float a3x = -2.f * q3x, a3y = -2.f * q3y, a3z = -2.f * q3z;
    __syncthreads();
    float b0 = 3.4e38f, b1 = 3.4e38f, b2 = 3.4e38f, b3 = 3.4e38f;
    int i0 = 0, i1 = 0, i2 = 0, i3 = 0;
#pragma unroll 4
    for (int j = 0; j < 256; ++j) {
      float4 c = sc[j];
      float t; bool cc;
      t = fmaf(c.x, a0x, c.w); t = fmaf(c.y, a0y, t); t = fmaf(c.z, a0z, t);
      cc = t < b0; b0 = cc ? t : b0; i0 = cc ? j : i0;
      t = fmaf(c.x, a1x, c.w); t = fmaf(c.y, a1y, t); t = fmaf(c.z, a1z, t);
      cc = t < b1; b1 = cc ? t : b1; i1 = cc ? j : i1;
      t = fmaf(c.x, a2x, c.w); t = fmaf(c.y, a2y, t); t = fmaf(c.z, a2z, t);
      cc = t < b2; b2 = cc ? t : b2; i2 = cc ? j : i2;
      t = fmaf(c.x, a3x, c.w); t = fmaf(c.y, a3y, t); t = fmaf(c.z, a3z, t);
      cc = t < b3; b3 = cc ? t : b3; i3 = cc ? j : i3;
    }
    int q = b * NN + m0;
    int base = seg * 256;
    atomicMin(&keys[q + 0], ((unsigned long long)fkey32(b0) << 32) | (unsigned)(base + i0));
    atomicMin(&keys[q + 1], ((unsigned long long)fkey32(b1) << 32) | (unsigned)(base + i1));
    atomicMin(&keys[q + 2], ((unsigned long long)fkey32(b2) << 32) | (unsigned)(base + i2));
    atomicMin(&keys[q + 3], ((unsigned long long)fkey32(b3) << 32) | (unsigned)(base + i3));
  }
}

// ------------- fused: postgather (blocks 0..63) + reduce mins (64..447) -
__global__ __launch_bounds__(256) void k_post(
    const float* __restrict__ ori_pre, const float* __restrict__ nor_pre,
    const float* __restrict__ gt, const unsigned long long* __restrict__ keys,
    const unsigned* __restrict__ rowmin, const unsigned* __restrict__ colmin,
    float* __restrict__ nor_gt, float* __restrict__ ori_pro, float* __restrict__ acc) {
  __shared__ float sb1[4], sb2[4];
  int blk = blockIdx.x;
  if (blk < 64) {
    int q = blk * 256 + threadIdx.x;
    int b = q >> 12;
    float ox = ori_pre[q * 3 + 0], oy = ori_pre[q * 3 + 1], oz = ori_pre[q * 3 + 2];
    float n1 = sqrtf(fmaf(ox, ox, fmaf(oy, oy, oz * oz)) + 1e-8f) + 1e-10f;
    ox /= n1; oy /= n1; oz /= n1;
    float px = nor_pre[q * 3 + 0], py = nor_pre[q * 3 + 1], pz = nor_pre[q * 3 + 2];
    float n2 = sqrtf(fmaf(px, px, fmaf(py, py, pz * pz)) + 1e-8f) + 1e-10f;
    px /= n2; py /= n2; pz /= n2;
    unsigned idx = (unsigned)(keys[q] & 0xffffffffULL);
    const float* g = gt + (size_t)b * NGG * 6 + (size_t)idx * 6 + 3;
    float gx = g[0], gy = g[1], gz = g[2];
    float dn = fmaf(gx, ox, fmaf(gy, oy, gz * oz));
    float vx = ox - gx * dn, vy = oy - gy * dn, vz = oz - gz * dn;
    float n3 = sqrtf(fmaf(vx, vx, fmaf(vy, vy, vz * vz)) + 1e-8f) + 1e-10f;
    vx /= n3; vy /= n3; vz /= n3;
    nor_gt[q * 3 + 0] = gx; nor_gt[q * 3 + 1] = gy; nor_gt[q * 3 + 2] = gz;
    ori_pro[q * 3 + 0] = vx; ori_pro[q * 3 + 1] = vy; ori_pro[q * 3 + 2] = vz;
    float na = fmaxf(sqrtf(fmaf(gx, gx, fmaf(gy, gy, gz * gz))), 1e-8f);
    float nb = fmaxf(sqrtf(fmaf(px, px, fmaf(py, py, pz * pz))), 1e-8f);
    float cs = fmaf(gx, px, fmaf(gy, py, gz * pz)) / (na * nb);
    float t_nor = 1.f - fabsf(cs);
    float t_ori = fabsf(dn);
    float s1 = block_sum_256(t_nor, sb1);
    float s2 = block_sum_256(t_ori, sb2);
    if (threadIdx.x == 0) {
      atomicAdd(&acc[1], s1);
      atomicAdd(&acc[2], s2);
    }
  } else {
    int rblk = blk - 64;   // [0,384)
    float v;
    int slot;
    if (rblk < 256) {
      int i = rblk * 256 + threadIdx.x;
      v = unfkey32(rowmin[i]);
      slot = (i >> 15) ? 5 : 3;   // 0=offset rows -> acc3, 1=up rows -> acc5
    } else {
      int i = (rblk - 256) * 256 + threadIdx.x;
      v = unfkey32(colmin[i]);
      slot = (i >> 14) ? 6 : 4;   // 0=offset cols -> acc4, 1=up cols -> acc6
    }
    float s = block_sum_256(v, sb1);
    if (threadIdx.x == 0) atomicAdd(&acc[slot], s);
  }
}

// ------------- KNN (K=6) + fused loss_smooth + last-block finalize -----
// Loop inversion: each thread OWNS 8 candidates in registers (no LDS
// candidate staging, no candidate ds_reads at all) and evaluates them
// against all 16 block-queries. tau_q = 6th smallest of the 8 wave-minima
// (each wave covers 512 disjoint candidates; the 6 smaller minima are 6
// distinct candidates <= tau => true 6th-best <= tau: exact pruning).
// Pass B re-evaluates (bitwise-identical FMAs) and pushes survivors
// (~10/query expected, 96 cap) into per-query LDS buffers; a 32-lane
// tournament then picks the 6 smallest u64 keys per query.
__global__ __launch_bounds__(512, 4) void k_knn_smooth(const float* __restrict__ pts,
                                                       const float* __restrict__ nor_gt,
                                                       const float* __restrict__ ori_pro,
                                                       float* __restrict__ acc,
                                                       float* __restrict__ out) {
  __shared__ unsigned long long surv[16][96];   // 12 KB
  __shared__ unsigned scnt[16];
  __shared__ float wmin[8][16];
  __shared__ float stau[16];
  __shared__ float sred[8];
  int tid = threadIdx.x;
  int lane = tid & 63;
  int wave = tid >> 6;
  int blk = blockIdx.x;
  int b = blk >> 8;                 // 256 blocks per batch
  const float* pb = pts + (size_t)b * NN * 3;

  if (tid < 16) scnt[tid] = 0;

  // ---- 16 query coords (uniform across block -> scalar regs) ----
  const float* pq = pb + (size_t)((blk & 255) * 16) * 3;
  float q2x[16], q2y[16], q2z[16];
#pragma unroll
  for (int qq = 0; qq < 16; ++qq) {
    q2x[qq] = -2.f * pq[qq * 3 + 0];
    q2y[qq] = -2.f * pq[qq * 3 + 1];
    q2z[qq] = -2.f * pq[qq * 3 + 2];
  }

  // ---- this thread's 8 candidates -> registers ----
  float cx[8], cy[8], cz[8], cw[8];
  {
    const float4* p4 = (const float4*)(pb + (size_t)tid * 24);
    float4 u0 = p4[0], u1 = p4[1], u2 = p4[2], u3 = p4[3], u4 = p4[4], u5 = p4[5];
    cx[0] = u0.x; cy[0] = u0.y; cz[0] = u0.z;
    cx[1] = u0.w; cy[1] = u1.x; cz[1] = u1.y;
    cx[2] = u1.z; cy[2] = u1.w; cz[2] = u2.x;
    cx[3] = u2.y; cy[3] = u2.z; cz[3] = u2.w;
    cx[4] = u3.x; cy[4] = u3.y; cz[4] = u3.z;
    cx[5] = u3.w; cy[5] = u4.x; cz[5] = u4.y;
    cx[6] = u4.z; cy[6] = u4.w; cz[6] = u5.x;
    cx[7] = u5.y; cy[7] = u5.z; cz[7] = u5.w;
#pragma unroll
    for (int c = 0; c < 8; ++c)
      cw[c] = fmaf(cx[c], cx[c], fmaf(cy[c], cy[c], cz[c] * cz[c]));
  }

  // ---- pass A: per-(thread,query) min over the 8 owned candidates ----
  float m[16];
#pragma unroll
  for (int qq = 0; qq < 16; ++qq) {
    float mm = 3.4e38f;
#pragma unroll
    for (int c = 0; c < 8; ++c) {
      float d = fmaf(cx[c], q2x[qq], cw[c]);
      d = fmaf(cy[c], q2y[qq], d);
      d = fmaf(cz[c], q2z[qq], d);
      mm = fminf(mm, d);
    }
    m[qq] = mm;
  }

  // ---- wave-min per query (512 disjoint candidates per wave) ----
#pragma unroll
  for (int qq = 0; qq < 16; ++qq) {
    float w = m[qq];
#pragma unroll
    for (int o = 32; o > 0; o >>= 1) w = fminf(w, __shfl_xor(w, o, 64));
    if (lane == 0) wmin[wave][qq] = w;
  }
  __syncthreads();

  // ---- tau_q = 6th smallest of the 8 wave minima (exact bound) ----
  if (tid < 16) {
    float vv[8];
#pragma unroll
    for (int i = 0; i < 8; ++i) vv[i] = wmin[i][tid];
    float tau = 3.4e38f;
#pragma unroll
    for (int i = 0; i < 8; ++i) {
      int cnt = 0;
#pragma unroll
      for (int j = 0; j < 8; ++j) cnt += (vv[j] <= vv[i]) ? 1 : 0;
      if (cnt >= 6) tau = fminf(tau, vv[i]);
    }
    stau[tid] = tau;
  }
  __syncthreads();

  // ---- pass B: survivors -> per-query LDS buffers ----
#pragma unroll
  for (int qq = 0; qq < 16; ++qq) {
    if (m[qq] <= stau[qq]) {     // thread has >=1 survivor for this query
      float tq = stau[qq];
#pragma unroll
      for (int c = 0; c < 8; ++c) {
        float d = fmaf(cx[c], q2x[qq], cw[c]);
        d = fmaf(cy[c], q2y[qq], d);
        d = fmaf(cz[c], q2z[qq], d);
        if (d <= tq) {
          unsigned slot = atomicAdd(&scnt[qq], 1u);
          if (slot < 96)
            surv[qq][slot] =
                ((unsigned long long)fkey32(d) << 32) | (unsigned)(tid * 8 + c);
        }
      }
    }
  }
  __syncthreads();

  // ---- selection: 32 lanes per query, 3-deep lists + 6-round tournament
  int q_local = tid >> 5;        // [0,16)
  int t = tid & 31;
  int q = blk * 16 + q_local;
  unsigned cnt = scnt[q_local];
  if (cnt > 96) cnt = 96;
  unsigned long long l0 = ~0ULL, l1 = ~0ULL, l2 = ~0ULL;
  for (int i = t; i < (int)cnt; i += 32) {
    unsigned long long k = surv[q_local][i];
    bool cc; unsigned long long nk;
    cc = k < l0; nk = cc ? k : l0; k = cc ? l0 : k; l0 = nk;
    cc = k < l1; nk = cc ? k : l1; k = cc ? l1 : k; l1 = nk;
    cc = k < l2; nk = cc ? k : l2;                  l2 = nk;
  }
  int myid = 0;
#pragma unroll
  for (int r = 0; r < 6; ++r) {
    unsigned long long h = l0, mk = l0;
#pragma unroll
    for (int o = 16; o > 0; o >>= 1) {
      unsigned long long other = __shfl_xor(mk, o, 32);
      mk = (other < mk) ? other : mk;
    }
    if (t == r) myid = (int)(mk & 0xffffffffULL);
    if (h == mk) { l0 = l1; l1 = l2; l2 = ~0ULL; }
  }

  float sum = 0.f;
  if (t < 6) {
    const float* gq = nor_gt + (size_t)q * 3;
    float ngx = gq[0], ngy = gq[1], ngz = gq[2];
    const float* oq = ori_pro + (size_t)q * 3;
    float box = oq[0], boy = oq[1], boz = oq[2];
    float rx = boy * ngz - boz * ngy;
    float ry = boz * ngx - box * ngz;
    float rz = box * ngy - boy * ngx;
    float nbo = fmaxf(sqrtf(fmaf(box, box, fmaf(boy, boy, boz * boz))), 1e-8f);
    float nrot = fmaxf(sqrtf(fmaf(rx, rx, fmaf(ry, ry, rz * rz))), 1e-8f);
    const float* gn = nor_gt + (size_t)(b * 4096 + myid) * 3;
    const float* go = ori_pro + (size_t)(b * 4096 + myid) * 3;
    float gnx = gn[0], gny = gn[1], gnz = gn[2];
    float gox = go[0], goy = go[1], goz = go[2];
    float ndv = fmaf(gnx, ngx, fmaf(gny, ngy, gnz * ngz));
    float wv = (expf(-ndv / 0.3f) * 10.f + 1.f) < 4.f ? 1.f : 5.f;
    float ngo = fmaxf(sqrtf(fmaf(gox, gox, fmaf(goy, goy, goz * goz))), 1e-8f);
    float c0 = fmaf(gox, box, fmaf(goy, boy, goz * boz)) / (ngo * nbo);
    float c1 = fmaf(gox, rx, fmaf(goy, ry, goz * rz)) / (ngo * nrot);
    float cosv = fminf(1.f - fabsf(c0), 1.f - fabsf(c1));
    sum = wv * cosv;
  }
  float s = block_sum_512(sum, sred);

  // ---- finalize: tid 0 only (fence count = gridDim, not threads) ----
  if (tid == 0) {
    atomicAdd(&acc[0], s);
    __threadfence();
    unsigned c = atomicAdd((unsigned*)(acc + 9), 1u);
    if (c == gridDim.x - 1) {
      __threadfence();
      float a0 = atomicAdd(&acc[0], 0.f);
      float a1 = atomicAdd(&acc[1], 0.f);
      float a2 = atomicAdd(&acc[2], 0.f);
      float a3 = atomicAdd(&acc[3], 0.f);
      float a4 = atomicAdd(&acc[4], 0.f);
      float a5 = atomicAdd(&acc[5], 0.f);
      float a6 = atomicAdd(&acc[6], 0.f);
      float loss_smooth = a0 / 98304.f;            // B*N*K
      float loss_nor = a1 / 16384.f;               // B*N
      float loss_nor_ori = a2 / 16384.f;
      float lco = a3 / 32768.f + a4 / 16384.f;     // B*NU rows + B*NG cols
      float lc = a5 / 32768.f + a6 / 16384.f;
      float loss_cd = lc + 0.4f * lco;
      float loss = loss_smooth + loss_nor + 0.1f * loss_nor_ori + 200.f * loss_cd;
      out[0] = loss;
      out[1] = loss_smooth;
      out[2] = loss_nor;
      out[3] = lco;
      out[4] = loss_nor_ori;
      out[5] = lc;
      out[6] = lc;
    }
  }
}

extern "C" void kernel_launch(void* const* d_in, const int* in_sizes, int n_in,
                              void* d_out, int out_size, void* d_ws, size_t ws_size,
                              hipStream_t stream) {
  (void)in_sizes; (void)n_in; (void)out_size; (void)ws_size;
  const float* ori_pre = (const float*)d_in[0];
  const float* nor_pre = (const float*)d_in[1];
  const float* xyz_up = (const float*)d_in[2];
  const float* xyz_off = (const float*)d_in[3];
  const float* pts = (const float*)d_in[4];
  const float* gt = (const float*)d_in[5];
  float* out = (float*)d_out;
  char* ws = (char*)d_ws;

  float* acc = (float*)(ws + 0);                                   // 16 floats: 0..6 sums, 9 done ctr
  unsigned long long* keys = (unsigned long long*)(ws + 512);      // 16384 u64 = 128 KB
  unsigned* rowmin = (unsigned*)(ws + 512 + 131072);               // 65536 u32 = 256 KB
  unsigned* colmin = (unsigned*)(ws + 512 + 131072 + 262144);      // 32768 u32 = 128 KB
  float* nor_gt = (float*)(ws + 512 + 131072 + 262144 + 131072);   // 49152 f32 = 192 KB
  float* ori_pro = (float*)(ws + 512 + 131072 + 262144 + 131072 + 196608);

  hipMemsetAsync(ws + 512, 0xFF, 131072 + 262144 + 131072, stream);

  k_scan<<<1280, 256, 0, stream>>>(pts, gt, xyz_up, xyz_off, keys, rowmin,
                                   colmin, acc);
  k_post<<<448, 256, 0, stream>>>(ori_pre, nor_pre, gt, keys, rowmin, colmin,
                                  nor_gt, ori_pro, acc);
  k_knn_smooth<<<1024, 512, 0, stream>>>(pts, nor_gt, ori_pro, acc, out);
}

// Round 12
// 170.508 us; speedup vs baseline: 1.3930x; 1.3930x over previous
//
#include <hip/hip_runtime.h>
#include <stdint.h>

#define NN 4096
#define NGG 4096
#define NUU 8192

// monotone float->uint mapping (order-preserving incl. negatives)
__device__ __forceinline__ unsigned fkey32(float f) {
  unsigned u = __float_as_uint(f);
  return u ^ (((int)u >> 31) | 0x80000000u);
}
__device__ __forceinline__ float unfkey32(unsigned k) {
  unsigned m = (k & 0x80000000u) ? 0x80000000u : 0xFFFFFFFFu;
  return __uint_as_float(k ^ m);
}

// ---------------- block-wide sum (blockDim.x == 256) -------------------
__device__ __forceinline__ float block_sum_256(float v, float* sbuf) {
#pragma unroll
  for (int o = 32; o > 0; o >>= 1) v += __shfl_down(v, o, 64);
  int lane = threadIdx.x & 63;
  int w = threadIdx.x >> 6;
  if (lane == 0) sbuf[w] = v;
  __syncthreads();
  float r = 0.f;
  if (threadIdx.x == 0) r = sbuf[0] + sbuf[1] + sbuf[2] + sbuf[3];
  __syncthreads();
  return r;
}

// ---------------- block-wide sum (blockDim.x == 512) -------------------
__device__ __forceinline__ float block_sum_512(float v, float* sbuf) {
#pragma unroll
  for (int o = 32; o > 0; o >>= 1) v += __shfl_down(v, o, 64);
  int lane = threadIdx.x & 63;
  int w = threadIdx.x >> 6;
  if (lane == 0) sbuf[w] = v;
  __syncthreads();
  float r = 0.f;
  if (threadIdx.x == 0) {
#pragma unroll
    for (int i = 0; i < 8; ++i) r += sbuf[i];
  }
  __syncthreads();
  return r;
}

// ---------------- fused scan: argmin + chamfer rows + chamfer cols -----
// R2-proven layout (Q=4, 1280 blocks, 256 thr). Block 0 zeroes acc.
__global__ __launch_bounds__(256) void k_scan(const float* __restrict__ pts,
                                              const float* __restrict__ gt,
                                              const float* __restrict__ up,
                                              const float* __restrict__ off,
                                              unsigned long long* __restrict__ keys,
                                              unsigned* __restrict__ rowmin,
                                              unsigned* __restrict__ colmin,
                                              float* __restrict__ acc) {
  __shared__ float4 sc[512];   // 8 KB
  int blk = blockIdx.x;
  int tid = threadIdx.x;
  if (blk == 0 && tid < 16) acc[tid] = 0.f;

  if (blk < 512) {
    // ------- cham_row: up/off points vs gt candidates -------
    int qb = blk >> 3;           // [0,64)
    int seg = blk & 7;           // [0,8)
    int wb = qb >> 3;            // [0,8)
    int which = wb >> 2;         // 0=off, 1=up
    int b = wb & 3;
    int r0 = (qb & 7) * 1024 + tid * 4;   // [0,8192)
    {
      const float* gtb = gt + (size_t)b * NGG * 6 + (size_t)seg * 512 * 6;
      int i0 = tid * 2;
      const float4* g4 = (const float4*)(gtb + (size_t)i0 * 6);
      float4 u0 = g4[0], u1 = g4[1], u2 = g4[2];
      sc[i0] = make_float4(u0.x, u0.y, u0.z,
                           fmaf(u0.x, u0.x, fmaf(u0.y, u0.y, u0.z * u0.z)));
      sc[i0 + 1] = make_float4(u1.z, u1.w, u2.x,
                               fmaf(u1.z, u1.z, fmaf(u1.w, u1.w, u2.x * u2.x)));
    }
    const float* src = which ? up : off;
    const float4* s4 = (const float4*)src;
    size_t fb = ((size_t)(b * NUU + r0) * 3) >> 2;
    float4 A = s4[fb], B = s4[fb + 1], C = s4[fb + 2];
    float q0x = A.x, q0y = A.y, q0z = A.z;
    float q1x = A.w, q1y = B.x, q1z = B.y;
    float q2x = B.z, q2y = B.w, q2z = C.x;
    float q3x = C.y, q3y = C.z, q3z = C.w;
    float qq0 = fmaf(q0x, q0x, fmaf(q0y, q0y, q0z * q0z));
    float qq1 = fmaf(q1x, q1x, fmaf(q1y, q1y, q1z * q1z));
    float qq2 = fmaf(q2x, q2x, fmaf(q2y, q2y, q2z * q2z));
    float qq3 = fmaf(q3x, q3x, fmaf(q3y, q3y, q3z * q3z));
    float a0x = -2.f * q0x, a0y = -2.f * q0y, a0z = -2.f * q0z;
    float a1x = -2.f * q1x, a1y = -2.f * q1y, a1z = -2.f * q1z;
    float a2x = -2.f * q2x, a2y = -2.f * q2y, a2z = -2.f * q2z;
    float a3x = -2.f * q3x, a3y = -2.f * q3y, a3z = -2.f * q3z;
    __syncthreads();
    float b0 = 3.4e38f, b1 = 3.4e38f, b2 = 3.4e38f, b3 = 3.4e38f;
#pragma unroll 4
    for (int j = 0; j < 512; ++j) {
      float4 c = sc[j];
      float t;
      t = fmaf(c.x, a0x, c.w); t = fmaf(c.y, a0y, t); t = fmaf(c.z, a0z, t); b0 = fminf(b0, t);
      t = fmaf(c.x, a1x, c.w); t = fmaf(c.y, a1y, t); t = fmaf(c.z, a1z, t); b1 = fminf(b1, t);
      t = fmaf(c.x, a2x, c.w); t = fmaf(c.y, a2y, t); t = fmaf(c.z, a2z, t); b2 = fminf(b2, t);
      t = fmaf(c.x, a3x, c.w); t = fmaf(c.y, a3y, t); t = fmaf(c.z, a3z, t); b3 = fminf(b3, t);
    }
    int gr = which * 32768 + b * NUU + r0;
    atomicMin(&rowmin[gr + 0], fkey32(b0 + qq0));
    atomicMin(&rowmin[gr + 1], fkey32(b1 + qq1));
    atomicMin(&rowmin[gr + 2], fkey32(b2 + qq2));
    atomicMin(&rowmin[gr + 3], fkey32(b3 + qq3));

  } else if (blk < 1024) {
    // ------- cham_col: gt points vs up/off candidates -------
    int blk2 = blk - 512;
    int qb = blk2 >> 4;          // [0,32)
    int seg = blk2 & 15;         // [0,16)
    int which = qb >> 4;         // 0=off, 1=up
    int b = (qb >> 2) & 3;
    int m0 = (qb & 3) * 1024 + tid * 4;   // [0,4096)
    const float* src = which ? up : off;
    if (tid < 128) {
      const float* sb = src + (size_t)b * NUU * 3 + (size_t)seg * 512 * 3;
      int i0 = tid * 4;
      const float4* s4 = (const float4*)(sb + (size_t)i0 * 3);
      float4 u0 = s4[0], u1 = s4[1], u2 = s4[2];
      sc[i0] = make_float4(u0.x, u0.y, u0.z,
                           fmaf(u0.x, u0.x, fmaf(u0.y, u0.y, u0.z * u0.z)));
      sc[i0 + 1] = make_float4(u0.w, u1.x, u1.y,
                               fmaf(u0.w, u0.w, fmaf(u1.x, u1.x, u1.y * u1.y)));
      sc[i0 + 2] = make_float4(u1.z, u1.w, u2.x,
                               fmaf(u1.z, u1.z, fmaf(u1.w, u1.w, u2.x * u2.x)));
      sc[i0 + 3] = make_float4(u2.y, u2.z, u2.w,
                               fmaf(u2.y, u2.y, fmaf(u2.z, u2.z, u2.w * u2.w)));
    }
    const float* g = gt + (size_t)b * NGG * 6 + (size_t)m0 * 6;
    float q0x = g[0],  q0y = g[1],  q0z = g[2];
    float q1x = g[6],  q1y = g[7],  q1z = g[8];
    float q2x = g[12], q2y = g[13], q2z = g[14];
    float q3x = g[18], q3y = g[19], q3z = g[20];
    float qq0 = fmaf(q0x, q0x, fmaf(q0y, q0y, q0z * q0z));
    float qq1 = fmaf(q1x, q1x, fmaf(q1y, q1y, q1z * q1z));
    float qq2 = fmaf(q2x, q2x, fmaf(q2y, q2y, q2z * q2z));
    float qq3 = fmaf(q3x, q3x, fmaf(q3y, q3y, q3z * q3z));
    float a0x = -2.f * q0x, a0y = -2.f * q0y, a0z = -2.f * q0z;
    float a1x = -2.f * q1x, a1y = -2.f * q1y, a1z = -2.f * q1z;
    float a2x = -2.f * q2x, a2y = -2.f * q2y, a2z = -2.f * q2z;
    float a3x = -2.f * q3x, a3y = -2.f * q3y, a3z = -2.f * q3z;
    __syncthreads();
    float b0 = 3.4e38f, b1 = 3.4e38f, b2 = 3.4e38f, b3 = 3.4e38f;
#pragma unroll 4
    for (int j = 0; j < 512; ++j) {
      float4 c = sc[j];
      float t;
      t = fmaf(c.x, a0x, c.w); t = fmaf(c.y, a0y, t); t = fmaf(c.z, a0z, t); b0 = fminf(b0, t);
      t = fmaf(c.x, a1x, c.w); t = fmaf(c.y, a1y, t); t = fmaf(c.z, a1z, t); b1 = fminf(b1, t);
      t = fmaf(c.x, a2x, c.w); t = fmaf(c.y, a2y, t); t = fmaf(c.z, a2z, t); b2 = fminf(b2, t);
      t = fmaf(c.x, a3x, c.w); t = fmaf(c.y, a3y, t); t = fmaf(c.z, a3z, t); b3 = fminf(b3, t);
    }
    int gc = which * 16384 + b * NGG + m0;
    atomicMin(&colmin[gc + 0], fkey32(b0 + qq0));
    atomicMin(&colmin[gc + 1], fkey32(b1 + qq1));
    atomicMin(&colmin[gc + 2], fkey32(b2 + qq2));
    atomicMin(&colmin[gc + 3], fkey32(b3 + qq3));

  } else {
    // ------- argmin: pts vs gt candidates (keyed: dist<<32 | idx) -------
    int blk3 = blk - 1024;
    int qb = blk3 >> 4;          // [0,16)
    int seg = blk3 & 15;         // [0,16), 256 candidates each
    int b = qb >> 2;
    int m0 = (qb & 3) * 1024 + tid * 4;   // [0,4096)
    if (tid < 128) {
      const float* gtb = gt + (size_t)b * NGG * 6 + (size_t)seg * 256 * 6;
      int i0 = tid * 2;
      const float4* g4 = (const float4*)(gtb + (size_t)i0 * 6);
      float4 u0 = g4[0], u1 = g4[1], u2 = g4[2];
      sc[i0] = make_float4(u0.x, u0.y, u0.z,
                           fmaf(u0.x, u0.x, fmaf(u0.y, u0.y, u0.z * u0.z)));
      sc[i0 + 1] = make_float4(u1.z, u1.w, u2.x,
                               fmaf(u1.z, u1.z, fmaf(u1.w, u1.w, u2.x * u2.x)));
    }
    size_t fb = ((size_t)(b * NN + m0) * 3) >> 2;
    const float4* p4 = (const float4*)pts;
    float4 A = p4[fb], B = p4[fb + 1], C = p4[fb + 2];
    float q0x = A.x, q0y = A.y, q0z = A.z;
    float q1x = A.w, q1y = B.x, q1z = B.y;
    float q2x = B.z, q2y = B.w, q2z = C.x;
    float q3x = C.y, q3y = C.z, q3z = C.w;
    float a0x = -2.f * q0x, a0y = -2.f * q0y, a0z = -2.f * q0z;
    float a1x = -2.f * q1x, a1y = -2.f * q1y, a1z = -2.f * q1z;
    float a2x = -2.f * q2x, a2y = -2.f * q2y, a2z = -2.f * q2z;
    float a3x = -2.f * q3x, a3y = -2.f * q3y, a3z = -2.f * q3z;
    __syncthreads();
    float b0 = 3.4e38f, b1 = 3.4e38f, b2 = 3.4e38f, b3 = 3.4e38f;
    int i0 = 0, i1 = 0, i2 = 0, i3 = 0;
#pragma unroll 4
    for (int j = 0; j < 256; ++j) {
      float4 c = sc[j];
      float t; bool cc;
      t = fmaf(c.x, a0x, c.w); t = fmaf(c.y, a0y, t); t = fmaf(c.z, a0z, t);
      cc = t < b0; b0 = cc ? t : b0; i0 = cc ? j : i0;
      t = fmaf(c.x, a1x, c.w); t = fmaf(c.y, a1y, t); t = fmaf(c.z, a1z, t);
      cc = t < b1; b1 = cc ? t : b1; i1 = cc ? j : i1;
      t = fmaf(c.x, a2x, c.w); t = fmaf(c.y, a2y, t); t = fmaf(c.z, a2z, t);
      cc = t < b2; b2 = cc ? t : b2; i2 = cc ? j : i2;
      t = fmaf(c.x, a3x, c.w); t = fmaf(c.y, a3y, t); t = fmaf(c.z, a3z, t);
      cc = t < b3; b3 = cc ? t : b3; i3 = cc ? j : i3;
    }
    int q = b * NN + m0;
    int base = seg * 256;
    atomicMin(&keys[q + 0], ((unsigned long long)fkey32(b0) << 32) | (unsigned)(base + i0));
    atomicMin(&keys[q + 1], ((unsigned long long)fkey32(b1) << 32) | (unsigned)(base + i1));
    atomicMin(&keys[q + 2], ((unsigned long long)fkey32(b2) << 32) | (unsigned)(base + i2));
    atomicMin(&keys[q + 3], ((unsigned long long)fkey32(b3) << 32) | (unsigned)(base + i3));
  }
}

// ------------- fused: postgather (blocks 0..63) + reduce mins (64..447) -
__global__ __launch_bounds__(256) void k_post(
    const float* __restrict__ ori_pre, const float* __restrict__ nor_pre,
    const float* __restrict__ gt, const unsigned long long* __restrict__ keys,
    const unsigned* __restrict__ rowmin, const unsigned* __restrict__ colmin,
    float* __restrict__ nor_gt, float* __restrict__ ori_pro, float* __restrict__ acc) {
  __shared__ float sb1[4], sb2[4];
  int blk = blockIdx.x;
  if (blk < 64) {
    int q = blk * 256 + threadIdx.x;
    int b = q >> 12;
    float ox = ori_pre[q * 3 + 0], oy = ori_pre[q * 3 + 1], oz = ori_pre[q * 3 + 2];
    float n1 = sqrtf(fmaf(ox, ox, fmaf(oy, oy, oz * oz)) + 1e-8f) + 1e-10f;
    ox /= n1; oy /= n1; oz /= n1;
    float px = nor_pre[q * 3 + 0], py = nor_pre[q * 3 + 1], pz = nor_pre[q * 3 + 2];
    float n2 = sqrtf(fmaf(px, px, fmaf(py, py, pz * pz)) + 1e-8f) + 1e-10f;
    px /= n2; py /= n2; pz /= n2;
    unsigned idx = (unsigned)(keys[q] & 0xffffffffULL);
    const float* g = gt + (size_t)b * NGG * 6 + (size_t)idx * 6 + 3;
    float gx = g[0], gy = g[1], gz = g[2];
    float dn = fmaf(gx, ox, fmaf(gy, oy, gz * oz));
    float vx = ox - gx * dn, vy = oy - gy * dn, vz = oz - gz * dn;
    float n3 = sqrtf(fmaf(vx, vx, fmaf(vy, vy, vz * vz)) + 1e-8f) + 1e-10f;
    vx /= n3; vy /= n3; vz /= n3;
    nor_gt[q * 3 + 0] = gx; nor_gt[q * 3 + 1] = gy; nor_gt[q * 3 + 2] = gz;
    ori_pro[q * 3 + 0] = vx; ori_pro[q * 3 + 1] = vy; ori_pro[q * 3 + 2] = vz;
    float na = fmaxf(sqrtf(fmaf(gx, gx, fmaf(gy, gy, gz * gz))), 1e-8f);
    float nb = fmaxf(sqrtf(fmaf(px, px, fmaf(py, py, pz * pz))), 1e-8f);
    float cs = fmaf(gx, px, fmaf(gy, py, gz * pz)) / (na * nb);
    float t_nor = 1.f - fabsf(cs);
    float t_ori = fabsf(dn);
    float s1 = block_sum_256(t_nor, sb1);
    float s2 = block_sum_256(t_ori, sb2);
    if (threadIdx.x == 0) {
      atomicAdd(&acc[1], s1);
      atomicAdd(&acc[2], s2);
    }
  } else {
    int rblk = blk - 64;   // [0,384)
    float v;
    int slot;
    if (rblk < 256) {
      int i = rblk * 256 + threadIdx.x;
      v = unfkey32(rowmin[i]);
      slot = (i >> 15) ? 5 : 3;   // 0=offset rows -> acc3, 1=up rows -> acc5
    } else {
      int i = (rblk - 256) * 256 + threadIdx.x;
      v = unfkey32(colmin[i]);
      slot = (i >> 14) ? 6 : 4;   // 0=offset cols -> acc4, 1=up cols -> acc6
    }
    float s = block_sum_256(v, sb1);
    if (threadIdx.x == 0) atomicAdd(&acc[slot], s);
  }
}

// ---- spill-proof helpers: ALL per-thread state in NAMED scalars ----
#define EV(i, QX, QY, QZ) \
  fmaf(c##i##z, (QZ), fmaf(c##i##y, (QY), fmaf(c##i##x, (QX), c##i##w)))

#define MIN8Q(QX, QY, QZ) \
  fminf(fminf(fminf(EV(0, QX, QY, QZ), EV(1, QX, QY, QZ)),                    \
              fminf(EV(2, QX, QY, QZ), EV(3, QX, QY, QZ))),                   \
        fminf(fminf(EV(4, QX, QY, QZ), EV(5, QX, QY, QZ)),                    \
              fminf(EV(6, QX, QY, QZ), EV(7, QX, QY, QZ))))

#define WREDMIN(M)                                            \
  {                                                           \
    M = fminf(M, __shfl_xor(M, 32, 64));                      \
    M = fminf(M, __shfl_xor(M, 16, 64));                      \
    M = fminf(M, __shfl_xor(M, 8, 64));                       \
    M = fminf(M, __shfl_xor(M, 4, 64));                       \
    M = fminf(M, __shfl_xor(M, 2, 64));                       \
    M = fminf(M, __shfl_xor(M, 1, 64));                       \
  }

#define PUSH1(QI, E, IDX)                                                     \
  if ((E) <= tq) {                                                            \
    unsigned sl = atomicAdd(&scnt[QI], 1u);                                   \
    if (sl < 96)                                                              \
      surv[QI][sl] = ((unsigned long long)fkey32(E) << 32) | (unsigned)(IDX); \
  }

#define PASSB_Q(QI, QX, QY, QZ)                                               \
  {                                                                           \
    float tq = stau[QI];                                                      \
    float e0 = EV(0, QX, QY, QZ), e1 = EV(1, QX, QY, QZ);                     \
    float e2 = EV(2, QX, QY, QZ), e3 = EV(3, QX, QY, QZ);                     \
    float e4 = EV(4, QX, QY, QZ), e5 = EV(5, QX, QY, QZ);                     \
    float e6 = EV(6, QX, QY, QZ), e7 = EV(7, QX, QY, QZ);                     \
    float mm = fminf(fminf(fminf(e0, e1), fminf(e2, e3)),                     \
                     fminf(fminf(e4, e5), fminf(e6, e7)));                    \
    if (mm <= tq) {                                                           \
      int base = tid * 8;                                                     \
      PUSH1(QI, e0, base + 0) PUSH1(QI, e1, base + 1)                         \
      PUSH1(QI, e2, base + 2) PUSH1(QI, e3, base + 3)                         \
      PUSH1(QI, e4, base + 4) PUSH1(QI, e5, base + 5)                         \
      PUSH1(QI, e6, base + 6) PUSH1(QI, e7, base + 7)                         \
    }                                                                         \
  }

#define TAUC(VI)                                                              \
  {                                                                           \
    int nct = (v0 <= (VI)) + (v1 <= (VI)) + (v2 <= (VI)) + (v3 <= (VI)) +     \
              (v4 <= (VI)) + (v5 <= (VI)) + (v6 <= (VI)) + (v7 <= (VI));      \
    if (nct >= 6) tau = fminf(tau, (VI));                                     \
  }

// ------------- KNN (K=6) + fused loss_smooth + last-block finalize -----
// Loop inversion (R11 algorithm, spill-proof codegen): each thread OWNS
// 8 candidates as 32 NAMED float regs; queries processed in 4 chunks of
// 4 NAMED query regs. tau_q = 6th smallest of the 8 wave-minima (each
// wave covers 512 disjoint candidates => >=6 distinct candidates <= tau
// => true 6th-best <= tau: exact). Pass B re-evaluates with identical
// FMA association and pushes survivors to per-query LDS buffers.
__global__ __launch_bounds__(512, 4) void k_knn_smooth(const float* __restrict__ pts,
                                                       const float* __restrict__ nor_gt,
                                                       const float* __restrict__ ori_pro,
                                                       float* __restrict__ acc,
                                                       float* __restrict__ out) {
  __shared__ unsigned long long surv[16][96];   // 12 KB
  __shared__ unsigned scnt[16];
  __shared__ float wmin[8][16];
  __shared__ float stau[16];
  __shared__ float sred[8];
  int tid = threadIdx.x;
  int lane = tid & 63;
  int wave = tid >> 6;
  int blk = blockIdx.x;
  int b = blk >> 8;                 // 256 blocks per batch
  const float* pb = pts + (size_t)b * NN * 3;
  const float* pq = pb + (size_t)((blk & 255) * 16) * 3;

  if (tid < 16) scnt[tid] = 0;

  // ---- this thread's 8 candidates -> 32 named registers ----
  float c0x, c0y, c0z, c0w, c1x, c1y, c1z, c1w, c2x, c2y, c2z, c2w,
      c3x, c3y, c3z, c3w, c4x, c4y, c4z, c4w, c5x, c5y, c5z, c5w,
      c6x, c6y, c6z, c6w, c7x, c7y, c7z, c7w;
  {
    const float4* p4 = (const float4*)(pb + (size_t)tid * 24);
    float4 u0 = p4[0], u1 = p4[1], u2 = p4[2], u3 = p4[3], u4 = p4[4], u5 = p4[5];
    c0x = u0.x; c0y = u0.y; c0z = u0.z;
    c1x = u0.w; c1y = u1.x; c1z = u1.y;
    c2x = u1.z; c2y = u1.w; c2z = u2.x;
    c3x = u2.y; c3y = u2.z; c3z = u2.w;
    c4x = u3.x; c4y = u3.y; c4z = u3.z;
    c5x = u3.w; c5y = u4.x; c5z = u4.y;
    c6x = u4.z; c6y = u4.w; c6z = u5.x;
    c7x = u5.y; c7y = u5.z; c7z = u5.w;
    c0w = fmaf(c0x, c0x, fmaf(c0y, c0y, c0z * c0z));
    c1w = fmaf(c1x, c1x, fmaf(c1y, c1y, c1z * c1z));
    c2w = fmaf(c2x, c2x, fmaf(c2y, c2y, c2z * c2z));
    c3w = fmaf(c3x, c3x, fmaf(c3y, c3y, c3z * c3z));
    c4w = fmaf(c4x, c4x, fmaf(c4y, c4y, c4z * c4z));
    c5w = fmaf(c5x, c5x, fmaf(c5y, c5y, c5z * c5z));
    c6w = fmaf(c6x, c6x, fmaf(c6y, c6y, c6z * c6z));
    c7w = fmaf(c7x, c7x, fmaf(c7y, c7y, c7z * c7z));
  }

  // ---- pass A: chunks of 4 queries, named scalars only ----
  for (int ch = 0; ch < 4; ++ch) {
    const float* qp = pq + ch * 12;
    float Q0x = -2.f * qp[0],  Q0y = -2.f * qp[1],  Q0z = -2.f * qp[2];
    float Q1x = -2.f * qp[3],  Q1y = -2.f * qp[4],  Q1z = -2.f * qp[5];
    float Q2x = -2.f * qp[6],  Q2y = -2.f * qp[7],  Q2z = -2.f * qp[8];
    float Q3x = -2.f * qp[9],  Q3y = -2.f * qp[10], Q3z = -2.f * qp[11];
    float m0 = MIN8Q(Q0x, Q0y, Q0z);
    float m1 = MIN8Q(Q1x, Q1y, Q1z);
    float m2 = MIN8Q(Q2x, Q2y, Q2z);
    float m3 = MIN8Q(Q3x, Q3y, Q3z);
    WREDMIN(m0) WREDMIN(m1) WREDMIN(m2) WREDMIN(m3)
    if (lane == 0) {
      wmin[wave][ch * 4 + 0] = m0;
      wmin[wave][ch * 4 + 1] = m1;
      wmin[wave][ch * 4 + 2] = m2;
      wmin[wave][ch * 4 + 3] = m3;
    }
  }
  __syncthreads();

  // ---- tau_q = 6th smallest of the 8 wave minima (exact bound) ----
  if (tid < 16) {
    float v0 = wmin[0][tid], v1 = wmin[1][tid], v2 = wmin[2][tid],
          v3 = wmin[3][tid], v4 = wmin[4][tid], v5 = wmin[5][tid],
          v6 = wmin[6][tid], v7 = wmin[7][tid];
    float tau = 3.4e38f;
    TAUC(v0) TAUC(v1) TAUC(v2) TAUC(v3) TAUC(v4) TAUC(v5) TAUC(v6) TAUC(v7)
    stau[tid] = tau;
  }
  __syncthreads();

  // ---- pass B: re-evaluate (identical FMA order), push survivors ----
  for (int ch = 0; ch < 4; ++ch) {
    const float* qp = pq + ch * 12;
    float Q0x = -2.f * qp[0],  Q0y = -2.f * qp[1],  Q0z = -2.f * qp[2];
    float Q1x = -2.f * qp[3],  Q1y = -2.f * qp[4],  Q1z = -2.f * qp[5];
    float Q2x = -2.f * qp[6],  Q2y = -2.f * qp[7],  Q2z = -2.f * qp[8];
    float Q3x = -2.f * qp[9],  Q3y = -2.f * qp[10], Q3z = -2.f * qp[11];
    PASSB_Q(ch * 4 + 0, Q0x, Q0y, Q0z)
    PASSB_Q(ch * 4 + 1, Q1x, Q1y, Q1z)
    PASSB_Q(ch * 4 + 2, Q2x, Q2y, Q2z)
    PASSB_Q(ch * 4 + 3, Q3x, Q3y, Q3z)
  }
  __syncthreads();

  // ---- selection: 32 lanes per query, 3-deep lists + 6-round tournament
  int q_local = tid >> 5;        // [0,16)
  int t = tid & 31;
  int q = blk * 16 + q_local;
  unsigned cnt = scnt[q_local];
  if (cnt > 96) cnt = 96;
  unsigned long long l0 = ~0ULL, l1 = ~0ULL, l2 = ~0ULL;
  for (int i = t; i < (int)cnt; i += 32) {
    unsigned long long k = surv[q_local][i];
    bool cc; unsigned long long nk;
    cc = k < l0; nk = cc ? k : l0; k = cc ? l0 : k; l0 = nk;
    cc = k < l1; nk = cc ? k : l1; k = cc ? l1 : k; l1 = nk;
    cc = k < l2; nk = cc ? k : l2;                  l2 = nk;
  }
  int myid = 0;
#pragma unroll
  for (int r = 0; r < 6; ++r) {
    unsigned long long h = l0, mk = l0;
#pragma unroll
    for (int o = 16; o > 0; o >>= 1) {
      unsigned long long other = __shfl_xor(mk, o, 32);
      mk = (other < mk) ? other : mk;
    }
    if (t == r) myid = (int)(mk & 0xffffffffULL);
    if (h == mk) { l0 = l1; l1 = l2; l2 = ~0ULL; }
  }

  float sum = 0.f;
  if (t < 6) {
    const float* gq = nor_gt + (size_t)q * 3;
    float ngx = gq[0], ngy = gq[1], ngz = gq[2];
    const float* oq = ori_pro + (size_t)q * 3;
    float box = oq[0], boy = oq[1], boz = oq[2];
    float rx = boy * ngz - boz * ngy;
    float ry = boz * ngx - box * ngz;
    float rz = box * ngy - boy * ngx;
    float nbo = fmaxf(sqrtf(fmaf(box, box, fmaf(boy, boy, boz * boz))), 1e-8f);
    float nrot = fmaxf(sqrtf(fmaf(rx, rx, fmaf(ry, ry, rz * rz))), 1e-8f);
    const float* gn = nor_gt + (size_t)(b * 4096 + myid) * 3;
    const float* go = ori_pro + (size_t)(b * 4096 + myid) * 3;
    float gnx = gn[0], gny = gn[1], gnz = gn[2];
    float gox = go[0], goy = go[1], goz = go[2];
    float ndv = fmaf(gnx, ngx, fmaf(gny, ngy, gnz * ngz));
    float wv = (expf(-ndv / 0.3f) * 10.f + 1.f) < 4.f ? 1.f : 5.f;
    float ngo = fmaxf(sqrtf(fmaf(gox, gox, fmaf(goy, goy, goz * goz))), 1e-8f);
    float c0 = fmaf(gox, box, fmaf(goy, boy, goz * boz)) / (ngo * nbo);
    float c1 = fmaf(gox, rx, fmaf(goy, ry, goz * rz)) / (ngo * nrot);
    float cosv = fminf(1.f - fabsf(c0), 1.f - fabsf(c1));
    sum = wv * cosv;
  }
  float s = block_sum_512(sum, sred);

  // ---- finalize: tid 0 only (fence count = gridDim, not threads) ----
  if (tid == 0) {
    atomicAdd(&acc[0], s);
    __threadfence();
    unsigned c = atomicAdd((unsigned*)(acc + 9), 1u);
    if (c == gridDim.x - 1) {
      __threadfence();
      float a0 = atomicAdd(&acc[0], 0.f);
      float a1 = atomicAdd(&acc[1], 0.f);
      float a2 = atomicAdd(&acc[2], 0.f);
      float a3 = atomicAdd(&acc[3], 0.f);
      float a4 = atomicAdd(&acc[4], 0.f);
      float a5 = atomicAdd(&acc[5], 0.f);
      float a6 = atomicAdd(&acc[6], 0.f);
      float loss_smooth = a0 / 98304.f;            // B*N*K
      float loss_nor = a1 / 16384.f;               // B*N
      float loss_nor_ori = a2 / 16384.f;
      float lco = a3 / 32768.f + a4 / 16384.f;     // B*NU rows + B*NG cols
      float lc = a5 / 32768.f + a6 / 16384.f;
      float loss_cd = lc + 0.4f * lco;
      float loss = loss_smooth + loss_nor + 0.1f * loss_nor_ori + 200.f * loss_cd;
      out[0] = loss;
      out[1] = loss_smooth;
      out[2] = loss_nor;
      out[3] = lco;
      out[4] = loss_nor_ori;
      out[5] = lc;
      out[6] = lc;
    }
  }
}

extern "C" void kernel_launch(void* const* d_in, const int* in_sizes, int n_in,
                              void* d_out, int out_size, void* d_ws, size_t ws_size,
                              hipStream_t stream) {
  (void)in_sizes; (void)n_in; (void)out_size; (void)ws_size;
  const float* ori_pre = (const float*)d_in[0];
  const float* nor_pre = (const float*)d_in[1];
  const float* xyz_up = (const float*)d_in[2];
  const float* xyz_off = (const float*)d_in[3];
  const float* pts = (const float*)d_in[4];
  const float* gt = (const float*)d_in[5];
  float* out = (float*)d_out;
  char* ws = (char*)d_ws;

  float* acc = (float*)(ws + 0);                                   // 16 floats: 0..6 sums, 9 done ctr
  unsigned long long* keys = (unsigned long long*)(ws + 512);      // 16384 u64 = 128 KB
  unsigned* rowmin = (unsigned*)(ws + 512 + 131072);               // 65536 u32 = 256 KB
  unsigned* colmin = (unsigned*)(ws + 512 + 131072 + 262144);      // 32768 u32 = 128 KB
  float* nor_gt = (float*)(ws + 512 + 131072 + 262144 + 131072);   // 49152 f32 = 192 KB
  float* ori_pro = (float*)(ws + 512 + 131072 + 262144 + 131072 + 196608);

  hipMemsetAsync(ws + 512, 0xFF, 131072 + 262144 + 131072, stream);

  k_scan<<<1280, 256, 0, stream>>>(pts, gt, xyz_up, xyz_off, keys, rowmin,
                                   colmin, acc);
  k_post<<<448, 256, 0, stream>>>(ori_pre, nor_pre, gt, keys, rowmin, colmin,
                                  nor_gt, ori_pro, acc);
  k_knn_smooth<<<1024, 512, 0, stream>>>(pts, nor_gt, ori_pro, acc, out);
}